// Round 4
// baseline (765.751 us; speedup 1.0000x reference)
//
#include <hip/hip_runtime.h>
#include <cstdint>

#define B_ 4
#define S_ 2048
#define D_ 512
#define H_ 8
#define DK_ 64
#define SCALE 0.125f
#define PSTR 68   // Ps LDS row stride in bf16 (scalar stores conflict-free)

using bfrag = __attribute__((ext_vector_type(8))) __bf16;
using f4    = __attribute__((ext_vector_type(4))) float;

#define MFMA16(a, b, c) __builtin_amdgcn_mfma_f32_16x16x32_bf16(a, b, c, 0, 0, 0)

// ---------------------------------------------------------------------------
// Weight transpose + split: WT[n][k] = W[k][c0+n], hi/lo bf16.
// ---------------------------------------------------------------------------
__global__ __launch_bounds__(256) void wtr(const float* __restrict__ W, int ldw, int c0,
                                           __bf16* __restrict__ th, __bf16* __restrict__ tl,
                                           int do_lo) {
  int idx = blockIdx.x * 256 + threadIdx.x;  // 512*512
  int k = idx & 511, n = idx >> 9;
  float x = W[(size_t)k * ldw + c0 + n];
  __bf16 h = (__bf16)x;
  th[(size_t)n * 512 + k] = h;
  if (do_lo) tl[(size_t)n * 512 + k] = (__bf16)(x - (float)h);
}

// ---------------------------------------------------------------------------
// Split-bf16 MFMA GEMM (unchanged — passed rounds 2/3).
// ---------------------------------------------------------------------------
template <bool AF32, bool BF32, bool LO, int MODE>
__global__ __launch_bounds__(256) void gemm_mfma(
    const void* __restrict__ Ap, const void* __restrict__ Bp, const void* __restrict__ Blop,
    float* __restrict__ Cf, __bf16* __restrict__ Oh, __bf16* __restrict__ Ol) {
  __shared__ __bf16 Ash[64 * 40];
  __shared__ __bf16 Asl[64 * 40];
  __shared__ __bf16 Bsh[64 * 40];
  __shared__ __bf16 Bsl[64 * 40];

  const int tid = threadIdx.x;
  const int m0 = blockIdx.y * 64, n0 = blockIdx.x * 64;
  const int row = tid >> 2, seg = tid & 3;
  const int lane = tid & 63, wv = tid >> 6;
  const int wm = (wv & 1) * 32, wn = (wv >> 1) * 32;
  const int qd = lane >> 4, ln = lane & 15;

  f4 acc[2][2];
#pragma unroll
  for (int i = 0; i < 2; i++)
#pragma unroll
    for (int j = 0; j < 2; j++)
#pragma unroll
      for (int r = 0; r < 4; r++) acc[i][j][r] = 0.f;

  for (int kt = 0; kt < 512; kt += 32) {
    const size_t abase = (size_t)(m0 + row) * 512 + kt + seg * 8;
    const size_t bbase = (size_t)(n0 + row) * 512 + kt + seg * 8;
    float4 a0, a1, b0, b1, bl0;
    if constexpr (AF32) {
      const float* A = (const float*)Ap;
      a0 = *(const float4*)&A[abase];
      a1 = *(const float4*)&A[abase + 4];
    } else {
      const __bf16* A = (const __bf16*)Ap;
      a0 = *(const float4*)&A[abase];
    }
    if constexpr (BF32) {
      const float* Bm = (const float*)Bp;
      b0 = *(const float4*)&Bm[bbase];
      b1 = *(const float4*)&Bm[bbase + 4];
    } else {
      const __bf16* Bm = (const __bf16*)Bp;
      b0 = *(const float4*)&Bm[bbase];
      if constexpr (LO) {
        const __bf16* Bl = (const __bf16*)Blop;
        bl0 = *(const float4*)&Bl[bbase];
      }
    }
    __syncthreads();
    if constexpr (AF32) {
      float x[8] = {a0.x, a0.y, a0.z, a0.w, a1.x, a1.y, a1.z, a1.w};
      bfrag h, l;
#pragma unroll
      for (int j = 0; j < 8; j++) {
        h[j] = (__bf16)x[j];
        l[j] = (__bf16)(x[j] - (float)h[j]);
      }
      *(bfrag*)&Ash[row * 40 + seg * 8] = h;
      if constexpr (LO) *(bfrag*)&Asl[row * 40 + seg * 8] = l;
    } else {
      *(float4*)&Ash[row * 40 + seg * 8] = a0;
    }
    if constexpr (BF32) {
      float x[8] = {b0.x, b0.y, b0.z, b0.w, b1.x, b1.y, b1.z, b1.w};
      bfrag h;
#pragma unroll
      for (int j = 0; j < 8; j++) h[j] = (__bf16)x[j];
      *(bfrag*)&Bsh[row * 40 + seg * 8] = h;
    } else {
      *(float4*)&Bsh[row * 40 + seg * 8] = b0;
      if constexpr (LO) *(float4*)&Bsl[row * 40 + seg * 8] = bl0;
    }
    __syncthreads();

    bfrag ah[2], al[2], bh[2], bl[2];
#pragma unroll
    for (int mi = 0; mi < 2; mi++) {
      ah[mi] = *(bfrag*)&Ash[(wm + mi * 16 + ln) * 40 + qd * 8];
      if constexpr (LO) al[mi] = *(bfrag*)&Asl[(wm + mi * 16 + ln) * 40 + qd * 8];
    }
#pragma unroll
    for (int ni = 0; ni < 2; ni++) {
      bh[ni] = *(bfrag*)&Bsh[(wn + ni * 16 + ln) * 40 + qd * 8];
      if constexpr (LO) bl[ni] = *(bfrag*)&Bsl[(wn + ni * 16 + ln) * 40 + qd * 8];
    }
#pragma unroll
    for (int mi = 0; mi < 2; mi++)
#pragma unroll
      for (int ni = 0; ni < 2; ni++) {
        acc[mi][ni] = MFMA16(ah[mi], bh[ni], acc[mi][ni]);
        if constexpr (LO) {
          acc[mi][ni] = MFMA16(ah[mi], bl[ni], acc[mi][ni]);
          acc[mi][ni] = MFMA16(al[mi], bh[ni], acc[mi][ni]);
        }
      }
  }

#pragma unroll
  for (int mi = 0; mi < 2; mi++)
#pragma unroll
    for (int ni = 0; ni < 2; ni++)
#pragma unroll
      for (int r = 0; r < 4; r++) {
        const int mrow = m0 + wm + mi * 16 + qd * 4 + r;
        const int ncol = n0 + wn + ni * 16 + ln;
        const float c = acc[mi][ni][r];
        if constexpr (MODE == 0) {
          Cf[(size_t)mrow * 512 + ncol] = c;
        } else if constexpr (MODE == 1) {
          const int b = mrow >> 11, s = mrow & (S_ - 1);
          const int h = ncol >> 6, dk = ncol & 63;
          const size_t o = (((size_t)b * H_ + h) * S_ + s) * DK_ + dk;
          __bf16 hh = (__bf16)c;
          Oh[o] = hh;
          Ol[o] = (__bf16)(c - (float)hh);
        } else {  // MODE 2: V^T
          const int h = mrow >> 6, dk = mrow & 63;
          const int b = ncol >> 11, s = ncol & (S_ - 1);
          Oh[(((size_t)b * H_ + h) * DK_ + dk) * S_ + s] = (__bf16)c;
        }
      }
}

// ---------------------------------------------------------------------------
// Fused flash attention, barrier-free: K/V MFMA fragments loaded DIRECTLY
// from global (b128, L1/L2-served) — no LDS staging, no __syncthreads.
// 4 waves x 16 q-rows = 64 q/block; grid (S/64, B*H) = 1024 blocks.
// Stores: ctx (bf16), final (m,l), E = exp(z - m_run) per tile (bf16),
// MT = running max per (row, tile) — consumed by mean_rescale.
// ---------------------------------------------------------------------------
__global__ __launch_bounds__(256, 3) void attn_fctx(
    const __bf16* __restrict__ Qh_, const __bf16* __restrict__ Ql_,
    const __bf16* __restrict__ Kh_, const __bf16* __restrict__ Kl_,
    const __bf16* __restrict__ VT, const float* __restrict__ mask,
    __bf16* __restrict__ CTXb, float* __restrict__ MR, float* __restrict__ LR,
    __bf16* __restrict__ E, float* __restrict__ MT) {
  __shared__ __bf16 Ps[64 * PSTR];
  const int tid = threadIdx.x, lane = tid & 63, wv = tid >> 6;
  const int qd = lane >> 4, ln = lane & 15;
  const int bh = blockIdx.y;
  const int q0b = blockIdx.x * 64;
  const int q0w = q0b + wv * 16;

  const __bf16* Kbh = Kh_ + (size_t)bh * S_ * DK_;
  const __bf16* Kbl = Kl_ + (size_t)bh * S_ * DK_;
  const __bf16* Vb = VT + (size_t)bh * DK_ * S_;

  bfrag qh[2], ql[2];
#pragma unroll
  for (int s = 0; s < 2; s++) {
    const size_t qb = ((size_t)bh * S_ + q0w + ln) * DK_ + s * 32 + qd * 8;
    qh[s] = *(const bfrag*)&Qh_[qb];
    ql[s] = *(const bfrag*)&Ql_[qb];
  }

  float m[4], l[4];
  f4 cacc[4];
#pragma unroll
  for (int r = 0; r < 4; r++) { m[r] = -3.0e38f; l[r] = 0.f; }
#pragma unroll
  for (int t = 0; t < 4; t++)
#pragma unroll
    for (int r = 0; r < 4; r++) cacc[t][r] = 0.f;

  for (int kt = 0; kt < S_; kt += 64) {
    // ---- QK^T: direct-global K fragments, split-3 MFMA ----
    f4 z[4];
#pragma unroll
    for (int t = 0; t < 4; t++)
#pragma unroll
      for (int r = 0; r < 4; r++) z[t][r] = 0.f;
#pragma unroll
    for (int t = 0; t < 4; t++)
#pragma unroll
      for (int s = 0; s < 2; s++) {
        const size_t ko = (size_t)(kt + t * 16 + ln) * DK_ + s * 32 + qd * 8;
        bfrag kbh = *(const bfrag*)&Kbh[ko];
        bfrag kbl = *(const bfrag*)&Kbl[ko];
        z[t] = MFMA16(qh[s], kbh, z[t]);
        z[t] = MFMA16(qh[s], kbl, z[t]);
        z[t] = MFMA16(ql[s], kbh, z[t]);
      }

    // ---- online softmax (rows = qd*4+r, cols = kt + t*16 + ln) ----
    float zf[4][4];
#pragma unroll
    for (int t = 0; t < 4; t++)
#pragma unroll
      for (int r = 0; r < 4; r++)
        zf[t][r] = fmaf(z[t][r], SCALE,
                        mask[(size_t)(q0w + qd * 4 + r) * S_ + kt + t * 16 + ln]);
#pragma unroll
    for (int r = 0; r < 4; r++) {
      float tm = fmaxf(fmaxf(zf[0][r], zf[1][r]), fmaxf(zf[2][r], zf[3][r]));
#pragma unroll
      for (int off = 1; off < 16; off <<= 1) tm = fmaxf(tm, __shfl_xor(tm, off, 64));
      const float nm = fmaxf(m[r], tm);
      const float al = __expf(m[r] - nm);
      m[r] = nm;
      float e0 = __expf(zf[0][r] - nm), e1 = __expf(zf[1][r] - nm);
      float e2 = __expf(zf[2][r] - nm), e3 = __expf(zf[3][r] - nm);
      const int prow = (wv * 16 + qd * 4 + r) * PSTR;
      Ps[prow + 0 * 16 + ln] = (__bf16)e0;
      Ps[prow + 1 * 16 + ln] = (__bf16)e1;
      Ps[prow + 2 * 16 + ln] = (__bf16)e2;
      Ps[prow + 3 * 16 + ln] = (__bf16)e3;
      l[r] = l[r] * al + (e0 + e1 + e2 + e3);  // lane-partial
#pragma unroll
      for (int t = 0; t < 4; t++) cacc[t][r] *= al;
    }
    if (ln == 0) {
#pragma unroll
      for (int r = 0; r < 4; r++)
        MT[((size_t)bh * 32 + (kt >> 6)) * S_ + q0w + qd * 4 + r] = m[r];
    }

    // ---- PV: P from wave-private LDS, V fragments direct from global ----
    bfrag pa[2];
#pragma unroll
    for (int s = 0; s < 2; s++)
      pa[s] = *(bfrag*)&Ps[(wv * 16 + ln) * PSTR + s * 32 + qd * 8];
#pragma unroll
    for (int t = 0; t < 4; t++)
#pragma unroll
      for (int s = 0; s < 2; s++) {
        bfrag vbf = *(const bfrag*)&Vb[(size_t)(t * 16 + ln) * S_ + kt + s * 32 + qd * 8];
        cacc[t] = MFMA16(pa[s], vbf, cacc[t]);
      }

    // ---- E copy: wave-private Ps rows -> global (vectorized) ----
#pragma unroll
    for (int c = 0; c < 2; c++) {
      const int row = wv * 16 + (lane >> 3) + c * 8;
      const int ch = lane & 7;
      float4 ev = *(float4*)&Ps[row * PSTR + ch * 8];
      *(float4*)&E[((size_t)bh * S_ + q0b + row) * S_ + kt + ch * 8] = ev;
    }
  }

  // ---- epilogue: reduce l across the 16-lane groups, write out ----
#pragma unroll
  for (int r = 0; r < 4; r++) {
    float ll = l[r];
#pragma unroll
    for (int off = 1; off < 16; off <<= 1) ll += __shfl_xor(ll, off, 64);
    l[r] = ll;
  }
  const int b = bh >> 3, h = bh & 7;
#pragma unroll
  for (int r = 0; r < 4; r++) {
    const float inv = 1.0f / l[r];
    const int s = q0w + qd * 4 + r;
#pragma unroll
    for (int t = 0; t < 4; t++)
      CTXb[((size_t)b * S_ + s) * D_ + h * DK_ + t * 16 + ln] = (__bf16)(cacc[t][r] * inv);
  }
  if (ln == 0) {
#pragma unroll
    for (int r = 0; r < 4; r++) {
      MR[(size_t)bh * S_ + q0w + qd * 4 + r] = m[r];
      LR[(size_t)bh * S_ + q0w + qd * 4 + r] = l[r];
    }
  }
}

// ---------------------------------------------------------------------------
// mean = (1/8) sum_h E * exp(MT - m_fin) / l_fin  — pure bandwidth kernel.
// Block 256: 32 q-rows x 8 segs of 8 k. Grid (S/32, B, 4 kv-slices).
// ---------------------------------------------------------------------------
__global__ __launch_bounds__(256) void mean_rescale(
    const __bf16* __restrict__ E, const float* __restrict__ MT,
    const float* __restrict__ MR, const float* __restrict__ LR,
    float* __restrict__ meanout) {
  const int t = threadIdx.x;
  const int qr = t >> 3, seg = t & 7;
  const int b = blockIdx.y, ks = blockIdx.z;
  const int qg = blockIdx.x * 32 + qr;

  for (int kc = 0; kc < 8; kc++) {
    const int k0 = ks * 512 + kc * 64;
    const int tk = k0 >> 6;
    float acc[8];
#pragma unroll
    for (int j = 0; j < 8; j++) acc[j] = 0.f;
    for (int h = 0; h < H_; h++) {
      const int bh = b * H_ + h;
      const float mf = MR[(size_t)bh * S_ + qg];
      const float il = 1.0f / LR[(size_t)bh * S_ + qg];
      const float mt = MT[((size_t)bh * 32 + tk) * S_ + qg];
      const float sc = __expf(mt - mf) * il;
      bfrag e = *(const bfrag*)&E[((size_t)bh * S_ + qg) * S_ + k0 + seg * 8];
#pragma unroll
      for (int j = 0; j < 8; j++) acc[j] += (float)e[j] * sc;
    }
    float4 o0, o1;
    o0.x = acc[0] * 0.125f; o0.y = acc[1] * 0.125f;
    o0.z = acc[2] * 0.125f; o0.w = acc[3] * 0.125f;
    o1.x = acc[4] * 0.125f; o1.y = acc[5] * 0.125f;
    o1.z = acc[6] * 0.125f; o1.w = acc[7] * 0.125f;
    float* mp = &meanout[((size_t)b * S_ + qg) * S_ + k0 + seg * 8];
    *(float4*)&mp[0] = o0;
    *(float4*)&mp[4] = o1;
  }
}

// ---------------------------------------------------------------------------
extern "C" void kernel_launch(void* const* d_in, const int* in_sizes, int n_in,
                              void* d_out, int out_size, void* d_ws, size_t ws_size,
                              hipStream_t stream) {
  (void)in_sizes; (void)n_in; (void)out_size; (void)ws_size;
  const float* Zq = (const float*)d_in[0];
  const float* Zkv = (const float*)d_in[1];
  const float* mask = (const float*)d_in[2];
  const float* Wqkv = (const float*)d_in[3];
  const float* Wout = (const float*)d_in[4];

  float* out = (float*)d_out;                // [B,S,D]
  float* mean = out + (size_t)B_ * S_ * D_;  // [B,S,S]

  char* w = (char*)d_ws;
  const size_t WSZ = 512 * 512 * sizeof(__bf16);
  const size_t QSZ = (size_t)B_ * H_ * S_ * DK_ * sizeof(__bf16);
  __bf16* WqTh = (__bf16*)w; w += WSZ;
  __bf16* WqTl = (__bf16*)w; w += WSZ;
  __bf16* WkTh = (__bf16*)w; w += WSZ;
  __bf16* WkTl = (__bf16*)w; w += WSZ;
  __bf16* WvTh = (__bf16*)w; w += WSZ;
  __bf16* WoTh = (__bf16*)w; w += WSZ;
  __bf16* Qh = (__bf16*)w; w += QSZ;
  __bf16* Ql = (__bf16*)w; w += QSZ;
  __bf16* Kh = (__bf16*)w; w += QSZ;
  __bf16* Kl = (__bf16*)w; w += QSZ;
  __bf16* VTh = (__bf16*)w; w += QSZ;
  __bf16* CTXb = (__bf16*)w; w += QSZ;
  float* MR = (float*)w; w += (size_t)B_ * H_ * S_ * sizeof(float);
  float* LR = (float*)w; w += (size_t)B_ * H_ * S_ * sizeof(float);
  float* MT = (float*)w; w += (size_t)B_ * H_ * 32 * S_ * sizeof(float);   // 8.4 MB
  __bf16* E = (__bf16*)w; w += (size_t)B_ * H_ * S_ * S_ * sizeof(__bf16); // 134 MB

  wtr<<<1024, 256, 0, stream>>>(Wqkv, 1536, 0, WqTh, WqTl, 1);
  wtr<<<1024, 256, 0, stream>>>(Wqkv, 1536, 512, WkTh, WkTl, 1);
  wtr<<<1024, 256, 0, stream>>>(Wqkv, 1536, 1024, WvTh, nullptr, 0);
  wtr<<<1024, 256, 0, stream>>>(Wout, 512, 0, WoTh, nullptr, 0);

  gemm_mfma<true, false, true, 1><<<dim3(8, 128), 256, 0, stream>>>(
      Zq, WqTh, WqTl, nullptr, Qh, Ql);
  gemm_mfma<true, false, true, 1><<<dim3(8, 128), 256, 0, stream>>>(
      Zkv, WkTh, WkTl, nullptr, Kh, Kl);
  gemm_mfma<false, true, false, 2><<<dim3(128, 8), 256, 0, stream>>>(
      WvTh, Zkv, nullptr, nullptr, VTh, nullptr);

  attn_fctx<<<dim3(32, 32), 256, 0, stream>>>(Qh, Ql, Kh, Kl, VTh, mask, CTXb, MR, LR, E, MT);
  mean_rescale<<<dim3(64, 4, 4), 256, 0, stream>>>(E, MT, MR, LR, mean);

  gemm_mfma<false, false, false, 0><<<dim3(8, 128), 256, 0, stream>>>(
      CTXb, WoTh, nullptr, out, nullptr, nullptr);
}

// Round 6
// 465.221 us; speedup vs baseline: 1.6460x; 1.6460x over previous
//
#include <hip/hip_runtime.h>
#include <cstdint>

#define B_ 4
#define S_ 2048
#define D_ 512
#define H_ 8
#define DK_ 64
#define SCALE 0.125f
#define KSTR 84   // K/V LDS row stride in bf16 (frag reads & staging conflict-free, measured R3)
#define PSTR 68   // Ps LDS row stride in bf16 (scalar stores conflict-free)

using bfrag = __attribute__((ext_vector_type(8))) __bf16;
using f4    = __attribute__((ext_vector_type(4))) float;

#define MFMA16(a, b, c) __builtin_amdgcn_mfma_f32_16x16x32_bf16(a, b, c, 0, 0, 0)

// ---------------------------------------------------------------------------
// Weight transpose + split: WT[n][k] = W[k][c0+n], hi/lo bf16.
// ---------------------------------------------------------------------------
__global__ __launch_bounds__(256) void wtr(const float* __restrict__ W, int ldw, int c0,
                                           __bf16* __restrict__ th, __bf16* __restrict__ tl,
                                           int do_lo) {
  int idx = blockIdx.x * 256 + threadIdx.x;  // 512*512
  int k = idx & 511, n = idx >> 9;
  float x = W[(size_t)k * ldw + c0 + n];
  __bf16 h = (__bf16)x;
  th[(size_t)n * 512 + k] = h;
  if (do_lo) tl[(size_t)n * 512 + k] = (__bf16)(x - (float)h);
}

// ---------------------------------------------------------------------------
// Split-bf16 MFMA GEMM (unchanged — passed rounds 2/3/4).
// ---------------------------------------------------------------------------
template <bool AF32, bool BF32, bool LO, int MODE>
__global__ __launch_bounds__(256) void gemm_mfma(
    const void* __restrict__ Ap, const void* __restrict__ Bp, const void* __restrict__ Blop,
    float* __restrict__ Cf, __bf16* __restrict__ Oh, __bf16* __restrict__ Ol) {
  __shared__ __bf16 Ash[64 * 40];
  __shared__ __bf16 Asl[64 * 40];
  __shared__ __bf16 Bsh[64 * 40];
  __shared__ __bf16 Bsl[64 * 40];

  const int tid = threadIdx.x;
  const int m0 = blockIdx.y * 64, n0 = blockIdx.x * 64;
  const int row = tid >> 2, seg = tid & 3;
  const int lane = tid & 63, wv = tid >> 6;
  const int wm = (wv & 1) * 32, wn = (wv >> 1) * 32;
  const int qd = lane >> 4, ln = lane & 15;

  f4 acc[2][2];
#pragma unroll
  for (int i = 0; i < 2; i++)
#pragma unroll
    for (int j = 0; j < 2; j++)
#pragma unroll
      for (int r = 0; r < 4; r++) acc[i][j][r] = 0.f;

  for (int kt = 0; kt < 512; kt += 32) {
    const size_t abase = (size_t)(m0 + row) * 512 + kt + seg * 8;
    const size_t bbase = (size_t)(n0 + row) * 512 + kt + seg * 8;
    float4 a0, a1, b0, b1, bl0;
    if constexpr (AF32) {
      const float* A = (const float*)Ap;
      a0 = *(const float4*)&A[abase];
      a1 = *(const float4*)&A[abase + 4];
    } else {
      const __bf16* A = (const __bf16*)Ap;
      a0 = *(const float4*)&A[abase];
    }
    if constexpr (BF32) {
      const float* Bm = (const float*)Bp;
      b0 = *(const float4*)&Bm[bbase];
      b1 = *(const float4*)&Bm[bbase + 4];
    } else {
      const __bf16* Bm = (const __bf16*)Bp;
      b0 = *(const float4*)&Bm[bbase];
      if constexpr (LO) {
        const __bf16* Bl = (const __bf16*)Blop;
        bl0 = *(const float4*)&Bl[bbase];
      }
    }
    __syncthreads();
    if constexpr (AF32) {
      float x[8] = {a0.x, a0.y, a0.z, a0.w, a1.x, a1.y, a1.z, a1.w};
      bfrag h, l;
#pragma unroll
      for (int j = 0; j < 8; j++) {
        h[j] = (__bf16)x[j];
        l[j] = (__bf16)(x[j] - (float)h[j]);
      }
      *(bfrag*)&Ash[row * 40 + seg * 8] = h;
      if constexpr (LO) *(bfrag*)&Asl[row * 40 + seg * 8] = l;
    } else {
      *(float4*)&Ash[row * 40 + seg * 8] = a0;
    }
    if constexpr (BF32) {
      float x[8] = {b0.x, b0.y, b0.z, b0.w, b1.x, b1.y, b1.z, b1.w};
      bfrag h;
#pragma unroll
      for (int j = 0; j < 8; j++) h[j] = (__bf16)x[j];
      *(bfrag*)&Bsh[row * 40 + seg * 8] = h;
    } else {
      *(float4*)&Bsh[row * 40 + seg * 8] = b0;
      if constexpr (LO) *(float4*)&Bsl[row * 40 + seg * 8] = bl0;
    }
    __syncthreads();

    bfrag ah[2], al[2], bh[2], bl[2];
#pragma unroll
    for (int mi = 0; mi < 2; mi++) {
      ah[mi] = *(bfrag*)&Ash[(wm + mi * 16 + ln) * 40 + qd * 8];
      if constexpr (LO) al[mi] = *(bfrag*)&Asl[(wm + mi * 16 + ln) * 40 + qd * 8];
    }
#pragma unroll
    for (int ni = 0; ni < 2; ni++) {
      bh[ni] = *(bfrag*)&Bsh[(wn + ni * 16 + ln) * 40 + qd * 8];
      if constexpr (LO) bl[ni] = *(bfrag*)&Bsl[(wn + ni * 16 + ln) * 40 + qd * 8];
    }
#pragma unroll
    for (int mi = 0; mi < 2; mi++)
#pragma unroll
      for (int ni = 0; ni < 2; ni++) {
        acc[mi][ni] = MFMA16(ah[mi], bh[ni], acc[mi][ni]);
        if constexpr (LO) {
          acc[mi][ni] = MFMA16(ah[mi], bl[ni], acc[mi][ni]);
          acc[mi][ni] = MFMA16(al[mi], bh[ni], acc[mi][ni]);
        }
      }
  }

#pragma unroll
  for (int mi = 0; mi < 2; mi++)
#pragma unroll
    for (int ni = 0; ni < 2; ni++)
#pragma unroll
      for (int r = 0; r < 4; r++) {
        const int mrow = m0 + wm + mi * 16 + qd * 4 + r;
        const int ncol = n0 + wn + ni * 16 + ln;
        const float c = acc[mi][ni][r];
        if constexpr (MODE == 0) {
          Cf[(size_t)mrow * 512 + ncol] = c;
        } else if constexpr (MODE == 1) {
          const int b = mrow >> 11, s = mrow & (S_ - 1);
          const int h = ncol >> 6, dk = ncol & 63;
          const size_t o = (((size_t)b * H_ + h) * S_ + s) * DK_ + dk;
          __bf16 hh = (__bf16)c;
          Oh[o] = hh;
          Ol[o] = (__bf16)(c - (float)hh);
        } else {  // MODE 2: V^T
          const int h = mrow >> 6, dk = mrow & 63;
          const int b = ncol >> 11, s = ncol & (S_ - 1);
          Oh[(((size_t)b * H_ + h) * DK_ + dk) * S_ + s] = (__bf16)c;
        }
      }
}

// ---------------------------------------------------------------------------
// Fused flash attention — round-2 LDS-staged structure + online softmax +
// E/MT side-channel for the mean kernel.
// 4 waves x 16 q-rows = 64 q/block; grid (S/64, B*H) = 1024 blocks.
// LDS: 3x(64*84) K/V tiles + 64*68 Ps = 40960 B -> 4 blocks/CU (160 KiB exact).
// ---------------------------------------------------------------------------
__global__ __launch_bounds__(256) void attn_fctx(
    const __bf16* __restrict__ Qh_, const __bf16* __restrict__ Ql_,
    const __bf16* __restrict__ Kh_, const __bf16* __restrict__ Kl_,
    const __bf16* __restrict__ VT, const float* __restrict__ mask,
    __bf16* __restrict__ CTXb, float* __restrict__ MR, float* __restrict__ LR,
    __bf16* __restrict__ E, float* __restrict__ MT) {
  __shared__ __bf16 Ksh[64 * KSTR];
  __shared__ __bf16 Ksl[64 * KSTR];
  __shared__ __bf16 Vs[64 * KSTR];
  __shared__ __bf16 Ps[64 * PSTR];
  const int tid = threadIdx.x, lane = tid & 63, wv = tid >> 6;
  const int qd = lane >> 4, ln = lane & 15;
  const int bh = blockIdx.y;
  const int q0b = blockIdx.x * 64;
  const int q0w = q0b + wv * 16;
  const int srow = tid >> 2, sseg = tid & 3;

  bfrag qh[2], ql[2];
#pragma unroll
  for (int s = 0; s < 2; s++) {
    const size_t qb = ((size_t)bh * S_ + q0w + ln) * DK_ + s * 32 + qd * 8;
    qh[s] = *(const bfrag*)&Qh_[qb];
    ql[s] = *(const bfrag*)&Ql_[qb];
  }

  float m[4], l[4];
  f4 cacc[4];
#pragma unroll
  for (int r = 0; r < 4; r++) { m[r] = -3.0e38f; l[r] = 0.f; }
#pragma unroll
  for (int t = 0; t < 4; t++)
#pragma unroll
    for (int r = 0; r < 4; r++) cacc[t][r] = 0.f;

  for (int kt = 0; kt < S_; kt += 64) {
    // ---- stage K hi/lo + V tile to LDS (coalesced float4) ----
    const size_t kb = ((size_t)bh * S_ + kt + srow) * DK_ + sseg * 16;
    const size_t vb = ((size_t)bh * DK_ + srow) * S_ + kt + sseg * 16;
    float4 h0 = *(const float4*)&Kh_[kb], h1 = *(const float4*)&Kh_[kb + 8];
    float4 l0 = *(const float4*)&Kl_[kb], l1 = *(const float4*)&Kl_[kb + 8];
    float4 v0 = *(const float4*)&VT[vb], v1 = *(const float4*)&VT[vb + 8];
    __syncthreads();
    *(float4*)&Ksh[srow * KSTR + sseg * 16] = h0;
    *(float4*)&Ksh[srow * KSTR + sseg * 16 + 8] = h1;
    *(float4*)&Ksl[srow * KSTR + sseg * 16] = l0;
    *(float4*)&Ksl[srow * KSTR + sseg * 16 + 8] = l1;
    *(float4*)&Vs[srow * KSTR + sseg * 16] = v0;
    *(float4*)&Vs[srow * KSTR + sseg * 16 + 8] = v1;
    __syncthreads();

    // ---- QK^T split-3 (24 MFMA) ----
    f4 z[4];
#pragma unroll
    for (int t = 0; t < 4; t++)
#pragma unroll
      for (int r = 0; r < 4; r++) z[t][r] = 0.f;
#pragma unroll
    for (int t = 0; t < 4; t++)
#pragma unroll
      for (int s = 0; s < 2; s++) {
        bfrag kbh = *(bfrag*)&Ksh[(t * 16 + ln) * KSTR + s * 32 + qd * 8];
        bfrag kbl = *(bfrag*)&Ksl[(t * 16 + ln) * KSTR + s * 32 + qd * 8];
        z[t] = MFMA16(qh[s], kbh, z[t]);
        z[t] = MFMA16(qh[s], kbl, z[t]);
        z[t] = MFMA16(ql[s], kbh, z[t]);
      }

    // ---- online softmax ----
    float zf[4][4];
#pragma unroll
    for (int t = 0; t < 4; t++)
#pragma unroll
      for (int r = 0; r < 4; r++)
        zf[t][r] = fmaf(z[t][r], SCALE,
                        mask[(size_t)(q0w + qd * 4 + r) * S_ + kt + t * 16 + ln]);
#pragma unroll
    for (int r = 0; r < 4; r++) {
      float tm = fmaxf(fmaxf(zf[0][r], zf[1][r]), fmaxf(zf[2][r], zf[3][r]));
#pragma unroll
      for (int off = 1; off < 16; off <<= 1) tm = fmaxf(tm, __shfl_xor(tm, off, 64));
      const float nm = fmaxf(m[r], tm);
      const float al = __expf(m[r] - nm);
      m[r] = nm;
      float e0 = __expf(zf[0][r] - nm), e1 = __expf(zf[1][r] - nm);
      float e2 = __expf(zf[2][r] - nm), e3 = __expf(zf[3][r] - nm);
      const int prow = (wv * 16 + qd * 4 + r) * PSTR;
      Ps[prow + 0 * 16 + ln] = (__bf16)e0;
      Ps[prow + 1 * 16 + ln] = (__bf16)e1;
      Ps[prow + 2 * 16 + ln] = (__bf16)e2;
      Ps[prow + 3 * 16 + ln] = (__bf16)e3;
      l[r] = l[r] * al + (e0 + e1 + e2 + e3);  // lane-partial
#pragma unroll
      for (int t = 0; t < 4; t++) cacc[t][r] *= al;
    }
    if (ln == 0) {
#pragma unroll
      for (int r = 0; r < 4; r++)
        MT[((size_t)bh * 32 + (kt >> 6)) * S_ + q0w + qd * 4 + r] = m[r];
    }

    // ---- PV (8 MFMA): P from wave-private Ps, V from LDS tile ----
    bfrag pa[2];
#pragma unroll
    for (int s = 0; s < 2; s++)
      pa[s] = *(bfrag*)&Ps[(wv * 16 + ln) * PSTR + s * 32 + qd * 8];
#pragma unroll
    for (int t = 0; t < 4; t++)
#pragma unroll
      for (int s = 0; s < 2; s++) {
        bfrag vbf = *(bfrag*)&Vs[(t * 16 + ln) * KSTR + s * 32 + qd * 8];
        cacc[t] = MFMA16(pa[s], vbf, cacc[t]);
      }

    // ---- E copy: wave-private Ps rows -> global (nontemporal, vectorized) ----
#pragma unroll
    for (int c = 0; c < 2; c++) {
      const int row = wv * 16 + (lane >> 3) + c * 8;
      const int ch = lane & 7;
      f4 ev = *(f4*)&Ps[row * PSTR + ch * 8];
      __builtin_nontemporal_store(
          ev, (f4*)&E[((size_t)bh * S_ + q0b + row) * S_ + kt + ch * 8]);
    }
  }

  // ---- epilogue ----
#pragma unroll
  for (int r = 0; r < 4; r++) {
    float ll = l[r];
#pragma unroll
    for (int off = 1; off < 16; off <<= 1) ll += __shfl_xor(ll, off, 64);
    l[r] = ll;
  }
  const int b = bh >> 3, h = bh & 7;
#pragma unroll
  for (int r = 0; r < 4; r++) {
    const float inv = 1.0f / l[r];
    const int s = q0w + qd * 4 + r;
#pragma unroll
    for (int t = 0; t < 4; t++)
      CTXb[((size_t)b * S_ + s) * D_ + h * DK_ + t * 16 + ln] = (__bf16)(cacc[t][r] * inv);
  }
  if (ln == 0) {
#pragma unroll
    for (int r = 0; r < 4; r++) {
      MR[(size_t)bh * S_ + q0w + qd * 4 + r] = m[r];
      LR[(size_t)bh * S_ + q0w + qd * 4 + r] = l[r];
    }
  }
}

// ---------------------------------------------------------------------------
// mean = (1/8) sum_h E * exp(MT - m_fin) / l_fin  — pure bandwidth kernel.
// Block 256: 32 q-rows x 8 segs of 8 k. Grid (S/32, B, 4 kv-slices).
// ---------------------------------------------------------------------------
__global__ __launch_bounds__(256) void mean_rescale(
    const __bf16* __restrict__ E, const float* __restrict__ MT,
    const float* __restrict__ MR, const float* __restrict__ LR,
    float* __restrict__ meanout) {
  const int t = threadIdx.x;
  const int qr = t >> 3, seg = t & 7;
  const int b = blockIdx.y, ks = blockIdx.z;
  const int qg = blockIdx.x * 32 + qr;

  for (int kc = 0; kc < 8; kc++) {
    const int k0 = ks * 512 + kc * 64;
    const int tk = k0 >> 6;
    float acc[8];
#pragma unroll
    for (int j = 0; j < 8; j++) acc[j] = 0.f;
    for (int h = 0; h < H_; h++) {
      const int bh = b * H_ + h;
      const float mf = MR[(size_t)bh * S_ + qg];
      const float il = 1.0f / LR[(size_t)bh * S_ + qg];
      const float mt = MT[((size_t)bh * 32 + tk) * S_ + qg];
      const float sc = __expf(mt - mf) * il;
      bfrag e = __builtin_nontemporal_load(
          (const bfrag*)&E[((size_t)bh * S_ + qg) * S_ + k0 + seg * 8]);
#pragma unroll
      for (int j = 0; j < 8; j++) acc[j] += (float)e[j] * sc;
    }
    f4 o0, o1;
    o0[0] = acc[0] * 0.125f; o0[1] = acc[1] * 0.125f;
    o0[2] = acc[2] * 0.125f; o0[3] = acc[3] * 0.125f;
    o1[0] = acc[4] * 0.125f; o1[1] = acc[5] * 0.125f;
    o1[2] = acc[6] * 0.125f; o1[3] = acc[7] * 0.125f;
    float* mp = &meanout[((size_t)b * S_ + qg) * S_ + k0 + seg * 8];
    *(f4*)&mp[0] = o0;
    *(f4*)&mp[4] = o1;
  }
}

// ---------------------------------------------------------------------------
extern "C" void kernel_launch(void* const* d_in, const int* in_sizes, int n_in,
                              void* d_out, int out_size, void* d_ws, size_t ws_size,
                              hipStream_t stream) {
  (void)in_sizes; (void)n_in; (void)out_size; (void)ws_size;
  const float* Zq = (const float*)d_in[0];
  const float* Zkv = (const float*)d_in[1];
  const float* mask = (const float*)d_in[2];
  const float* Wqkv = (const float*)d_in[3];
  const float* Wout = (const float*)d_in[4];

  float* out = (float*)d_out;                // [B,S,D]
  float* mean = out + (size_t)B_ * S_ * D_;  // [B,S,S]

  char* w = (char*)d_ws;
  const size_t WSZ = 512 * 512 * sizeof(__bf16);
  const size_t QSZ = (size_t)B_ * H_ * S_ * DK_ * sizeof(__bf16);
  __bf16* WqTh = (__bf16*)w; w += WSZ;
  __bf16* WqTl = (__bf16*)w; w += WSZ;
  __bf16* WkTh = (__bf16*)w; w += WSZ;
  __bf16* WkTl = (__bf16*)w; w += WSZ;
  __bf16* WvTh = (__bf16*)w; w += WSZ;
  __bf16* WoTh = (__bf16*)w; w += WSZ;
  __bf16* Qh = (__bf16*)w; w += QSZ;
  __bf16* Ql = (__bf16*)w; w += QSZ;
  __bf16* Kh = (__bf16*)w; w += QSZ;
  __bf16* Kl = (__bf16*)w; w += QSZ;
  __bf16* VTh = (__bf16*)w; w += QSZ;
  __bf16* CTXb = (__bf16*)w; w += QSZ;
  float* MR = (float*)w; w += (size_t)B_ * H_ * S_ * sizeof(float);
  float* LR = (float*)w; w += (size_t)B_ * H_ * S_ * sizeof(float);
  float* MT = (float*)w; w += (size_t)B_ * H_ * 32 * S_ * sizeof(float);   // 8.4 MB
  __bf16* E = (__bf16*)w; w += (size_t)B_ * H_ * S_ * S_ * sizeof(__bf16); // 134 MB

  wtr<<<1024, 256, 0, stream>>>(Wqkv, 1536, 0, WqTh, WqTl, 1);
  wtr<<<1024, 256, 0, stream>>>(Wqkv, 1536, 512, WkTh, WkTl, 1);
  wtr<<<1024, 256, 0, stream>>>(Wqkv, 1536, 1024, WvTh, nullptr, 0);
  wtr<<<1024, 256, 0, stream>>>(Wout, 512, 0, WoTh, nullptr, 0);

  gemm_mfma<true, false, true, 1><<<dim3(8, 128), 256, 0, stream>>>(
      Zq, WqTh, WqTl, nullptr, Qh, Ql);
  gemm_mfma<true, false, true, 1><<<dim3(8, 128), 256, 0, stream>>>(
      Zkv, WkTh, WkTl, nullptr, Kh, Kl);
  gemm_mfma<false, true, false, 2><<<dim3(128, 8), 256, 0, stream>>>(
      WvTh, Zkv, nullptr, nullptr, VTh, nullptr);

  attn_fctx<<<dim3(32, 32), 256, 0, stream>>>(Qh, Ql, Kh, Kl, VTh, mask, CTXb, MR, LR, E, MT);
  mean_rescale<<<dim3(64, 4, 4), 256, 0, stream>>>(E, MT, MR, LR, mean);

  gemm_mfma<false, false, false, 0><<<dim3(8, 128), 256, 0, stream>>>(
      CTXb, WoTh, nullptr, out, nullptr, nullptr);
}

// Round 8
// 413.812 us; speedup vs baseline: 1.8505x; 1.1242x over previous
//
#include <hip/hip_runtime.h>
#include <cstdint>

#define B_ 4
#define S_ 2048
#define D_ 512
#define H_ 8
#define DK_ 64
#define SCALE 0.125f
#define KSTR 84   // K/V LDS row stride in bf16 (frag reads & staging conflict-free, measured)
#define PSTR 68   // Ps LDS row stride in bf16

using bfrag = __attribute__((ext_vector_type(8))) __bf16;
using b4    = __attribute__((ext_vector_type(4))) __bf16;
using f4    = __attribute__((ext_vector_type(4))) float;

#define MFMA16(a, b, c) __builtin_amdgcn_mfma_f32_16x16x32_bf16(a, b, c, 0, 0, 0)

// ---------------------------------------------------------------------------
// Weight transpose + split: WT[n][k] = W[k][c0+n], hi/lo bf16.
// ---------------------------------------------------------------------------
__global__ __launch_bounds__(256) void wtr(const float* __restrict__ W, int ldw, int c0,
                                           __bf16* __restrict__ th, __bf16* __restrict__ tl,
                                           int do_lo) {
  int idx = blockIdx.x * 256 + threadIdx.x;  // 512*512
  int k = idx & 511, n = idx >> 9;
  float x = W[(size_t)k * ldw + c0 + n];
  __bf16 h = (__bf16)x;
  th[(size_t)n * 512 + k] = h;
  if (do_lo) tl[(size_t)n * 512 + k] = (__bf16)(x - (float)h);
}

// ---------------------------------------------------------------------------
// Split-bf16 MFMA GEMM (unchanged — passed rounds 2/3/4/6).
// ---------------------------------------------------------------------------
template <bool AF32, bool BF32, bool LO, int MODE>
__global__ __launch_bounds__(256) void gemm_mfma(
    const void* __restrict__ Ap, const void* __restrict__ Bp, const void* __restrict__ Blop,
    float* __restrict__ Cf, __bf16* __restrict__ Oh, __bf16* __restrict__ Ol) {
  __shared__ __bf16 Ash[64 * 40];
  __shared__ __bf16 Asl[64 * 40];
  __shared__ __bf16 Bsh[64 * 40];
  __shared__ __bf16 Bsl[64 * 40];

  const int tid = threadIdx.x;
  const int m0 = blockIdx.y * 64, n0 = blockIdx.x * 64;
  const int row = tid >> 2, seg = tid & 3;
  const int lane = tid & 63, wv = tid >> 6;
  const int wm = (wv & 1) * 32, wn = (wv >> 1) * 32;
  const int qd = lane >> 4, ln = lane & 15;

  f4 acc[2][2];
#pragma unroll
  for (int i = 0; i < 2; i++)
#pragma unroll
    for (int j = 0; j < 2; j++)
#pragma unroll
      for (int r = 0; r < 4; r++) acc[i][j][r] = 0.f;

  for (int kt = 0; kt < 512; kt += 32) {
    const size_t abase = (size_t)(m0 + row) * 512 + kt + seg * 8;
    const size_t bbase = (size_t)(n0 + row) * 512 + kt + seg * 8;
    float4 a0, a1, b0, b1, bl0;
    if constexpr (AF32) {
      const float* A = (const float*)Ap;
      a0 = *(const float4*)&A[abase];
      a1 = *(const float4*)&A[abase + 4];
    } else {
      const __bf16* A = (const __bf16*)Ap;
      a0 = *(const float4*)&A[abase];
    }
    if constexpr (BF32) {
      const float* Bm = (const float*)Bp;
      b0 = *(const float4*)&Bm[bbase];
      b1 = *(const float4*)&Bm[bbase + 4];
    } else {
      const __bf16* Bm = (const __bf16*)Bp;
      b0 = *(const float4*)&Bm[bbase];
      if constexpr (LO) {
        const __bf16* Bl = (const __bf16*)Blop;
        bl0 = *(const float4*)&Bl[bbase];
      }
    }
    __syncthreads();
    if constexpr (AF32) {
      float x[8] = {a0.x, a0.y, a0.z, a0.w, a1.x, a1.y, a1.z, a1.w};
      bfrag h, l;
#pragma unroll
      for (int j = 0; j < 8; j++) {
        h[j] = (__bf16)x[j];
        l[j] = (__bf16)(x[j] - (float)h[j]);
      }
      *(bfrag*)&Ash[row * 40 + seg * 8] = h;
      if constexpr (LO) *(bfrag*)&Asl[row * 40 + seg * 8] = l;
    } else {
      *(float4*)&Ash[row * 40 + seg * 8] = a0;
    }
    if constexpr (BF32) {
      float x[8] = {b0.x, b0.y, b0.z, b0.w, b1.x, b1.y, b1.z, b1.w};
      bfrag h;
#pragma unroll
      for (int j = 0; j < 8; j++) h[j] = (__bf16)x[j];
      *(bfrag*)&Bsh[row * 40 + seg * 8] = h;
    } else {
      *(float4*)&Bsh[row * 40 + seg * 8] = b0;
      if constexpr (LO) *(float4*)&Bsl[row * 40 + seg * 8] = bl0;
    }
    __syncthreads();

    bfrag ah[2], al[2], bh[2], bl[2];
#pragma unroll
    for (int mi = 0; mi < 2; mi++) {
      ah[mi] = *(bfrag*)&Ash[(wm + mi * 16 + ln) * 40 + qd * 8];
      if constexpr (LO) al[mi] = *(bfrag*)&Asl[(wm + mi * 16 + ln) * 40 + qd * 8];
    }
#pragma unroll
    for (int ni = 0; ni < 2; ni++) {
      bh[ni] = *(bfrag*)&Bsh[(wn + ni * 16 + ln) * 40 + qd * 8];
      if constexpr (LO) bl[ni] = *(bfrag*)&Bsl[(wn + ni * 16 + ln) * 40 + qd * 8];
    }
#pragma unroll
    for (int mi = 0; mi < 2; mi++)
#pragma unroll
      for (int ni = 0; ni < 2; ni++) {
        acc[mi][ni] = MFMA16(ah[mi], bh[ni], acc[mi][ni]);
        if constexpr (LO) {
          acc[mi][ni] = MFMA16(ah[mi], bl[ni], acc[mi][ni]);
          acc[mi][ni] = MFMA16(al[mi], bh[ni], acc[mi][ni]);
        }
      }
  }

#pragma unroll
  for (int mi = 0; mi < 2; mi++)
#pragma unroll
    for (int ni = 0; ni < 2; ni++)
#pragma unroll
      for (int r = 0; r < 4; r++) {
        const int mrow = m0 + wm + mi * 16 + qd * 4 + r;
        const int ncol = n0 + wn + ni * 16 + ln;
        const float c = acc[mi][ni][r];
        if constexpr (MODE == 0) {
          Cf[(size_t)mrow * 512 + ncol] = c;
        } else if constexpr (MODE == 1) {
          const int b = mrow >> 11, s = mrow & (S_ - 1);
          const int h = ncol >> 6, dk = ncol & 63;
          const size_t o = (((size_t)b * H_ + h) * S_ + s) * DK_ + dk;
          __bf16 hh = (__bf16)c;
          Oh[o] = hh;
          Ol[o] = (__bf16)(c - (float)hh);
        } else {  // MODE 2: V^T
          const int h = mrow >> 6, dk = mrow & 63;
          const int b = ncol >> 11, s = ncol & (S_ - 1);
          Oh[(((size_t)b * H_ + h) * DK_ + dk) * S_ + s] = (__bf16)c;
        }
      }
}

// ---------------------------------------------------------------------------
// Fused flash attention, transposed-score variant:
// z^T = K·Q^T (swapped MFMA operands; same LDS read patterns) puts q on lanes,
// kv on regs — softmax (m,l) is scalar/lane, tile reduce = 2 shfl_xor.
// Mask read directly in transposed order (float4/lane/t, zero-mask L2-hot).
// Ps transpose: 4 packed ds_write_b64/iter. Next K/V tile prefetched to regs.
// 4 waves x 16 q; grid (S/64, B*H) = 1024 blocks; LDS 40960 B (4 blocks/CU).
// ---------------------------------------------------------------------------
__global__ __launch_bounds__(256) void attn_fctx(
    const __bf16* __restrict__ Qh_, const __bf16* __restrict__ Ql_,
    const __bf16* __restrict__ Kh_, const __bf16* __restrict__ Kl_,
    const __bf16* __restrict__ VT, const float* __restrict__ mask,
    __bf16* __restrict__ CTXb, float* __restrict__ MR, float* __restrict__ LR,
    __bf16* __restrict__ E, float* __restrict__ MT) {
  __shared__ __bf16 Ksh[64 * KSTR];
  __shared__ __bf16 Ksl[64 * KSTR];
  __shared__ __bf16 Vs[64 * KSTR];
  __shared__ __bf16 Ps[64 * PSTR];
  const int tid = threadIdx.x, lane = tid & 63, wv = tid >> 6;
  const int qd = lane >> 4, ln = lane & 15;
  const int bh = blockIdx.y;
  const int q0b = blockIdx.x * 64;
  const int q0w = q0b + wv * 16;
  const int srow = tid >> 2, sseg = tid & 3;

  bfrag qh[2], ql[2];
#pragma unroll
  for (int s = 0; s < 2; s++) {
    const size_t qb = ((size_t)bh * S_ + q0w + ln) * DK_ + s * 32 + qd * 8;
    qh[s] = *(const bfrag*)&Qh_[qb];
    ql[s] = *(const bfrag*)&Ql_[qb];
  }

  float m = -3.0e38f, l = 0.f;   // scalar per lane: q-column = q0w + ln
  f4 cacc[4];
#pragma unroll
  for (int t = 0; t < 4; t++)
#pragma unroll
    for (int r = 0; r < 4; r++) cacc[t][r] = 0.f;

  // prefetch tile 0
  float4 h0, h1, l0, l1, v0, v1;
  {
    const size_t kb = ((size_t)bh * S_ + srow) * DK_ + sseg * 16;
    const size_t vb = ((size_t)bh * DK_ + srow) * S_ + sseg * 16;
    h0 = *(const float4*)&Kh_[kb]; h1 = *(const float4*)&Kh_[kb + 8];
    l0 = *(const float4*)&Kl_[kb]; l1 = *(const float4*)&Kl_[kb + 8];
    v0 = *(const float4*)&VT[vb];  v1 = *(const float4*)&VT[vb + 8];
  }

  for (int kt = 0; kt < S_; kt += 64) {
    __syncthreads();
    *(float4*)&Ksh[srow * KSTR + sseg * 16] = h0;
    *(float4*)&Ksh[srow * KSTR + sseg * 16 + 8] = h1;
    *(float4*)&Ksl[srow * KSTR + sseg * 16] = l0;
    *(float4*)&Ksl[srow * KSTR + sseg * 16 + 8] = l1;
    *(float4*)&Vs[srow * KSTR + sseg * 16] = v0;
    *(float4*)&Vs[srow * KSTR + sseg * 16 + 8] = v1;
    __syncthreads();

    // mask in transposed order: entry (kv = kt + t*16 + qd*4 + r, q = q0w + ln)
    f4 mk[4];
#pragma unroll
    for (int t = 0; t < 4; t++)
      mk[t] = *(const f4*)&mask[(size_t)(q0w + ln) * S_ + kt + t * 16 + qd * 4];

    // prefetch next tile while computing this one
    if (kt + 64 < S_) {
      const size_t kb = ((size_t)bh * S_ + kt + 64 + srow) * DK_ + sseg * 16;
      const size_t vb = ((size_t)bh * DK_ + srow) * S_ + kt + 64 + sseg * 16;
      h0 = *(const float4*)&Kh_[kb]; h1 = *(const float4*)&Kh_[kb + 8];
      l0 = *(const float4*)&Kl_[kb]; l1 = *(const float4*)&Kl_[kb + 8];
      v0 = *(const float4*)&VT[vb];  v1 = *(const float4*)&VT[vb + 8];
    }

    // ---- z^T = K·Q^T, split-3 (24 MFMA); reads identical to old pattern ----
    f4 z[4];
#pragma unroll
    for (int t = 0; t < 4; t++)
#pragma unroll
      for (int r = 0; r < 4; r++) z[t][r] = 0.f;
#pragma unroll
    for (int t = 0; t < 4; t++)
#pragma unroll
      for (int s = 0; s < 2; s++) {
        bfrag kbh = *(bfrag*)&Ksh[(t * 16 + ln) * KSTR + s * 32 + qd * 8];
        bfrag kbl = *(bfrag*)&Ksl[(t * 16 + ln) * KSTR + s * 32 + qd * 8];
        z[t] = MFMA16(kbh, qh[s], z[t]);   // Kh·Qh
        z[t] = MFMA16(kbl, qh[s], z[t]);   // Kl·Qh
        z[t] = MFMA16(kbh, ql[s], z[t]);   // Kh·Ql
      }

    // ---- softmax over per-lane q column ----
    float zf[4][4];
#pragma unroll
    for (int t = 0; t < 4; t++)
#pragma unroll
      for (int r = 0; r < 4; r++)
        zf[t][r] = fmaf(z[t][r], SCALE, mk[t][r]);

    float tm = zf[0][0];
#pragma unroll
    for (int t = 0; t < 4; t++)
#pragma unroll
      for (int r = 0; r < 4; r++) tm = fmaxf(tm, zf[t][r]);
    tm = fmaxf(tm, __shfl_xor(tm, 16, 64));
    tm = fmaxf(tm, __shfl_xor(tm, 32, 64));
    const float nm = fmaxf(m, tm);
    const float al = __expf(m - nm);
    m = nm;

    float ls = 0.f;
#pragma unroll
    for (int t = 0; t < 4; t++) {
      float e0 = __expf(zf[t][0] - nm), e1 = __expf(zf[t][1] - nm);
      float e2 = __expf(zf[t][2] - nm), e3 = __expf(zf[t][3] - nm);
      ls += (e0 + e1) + (e2 + e3);
      b4 pk;
      pk[0] = (__bf16)e0; pk[1] = (__bf16)e1;
      pk[2] = (__bf16)e2; pk[3] = (__bf16)e3;
      *(b4*)&Ps[(wv * 16 + ln) * PSTR + t * 16 + qd * 4] = pk;  // ds_write_b64
    }
    l = l * al + ls;

    if (qd == 0)
      MT[((size_t)bh * 32 + (kt >> 6)) * S_ + q0w + ln] = m;

    // ---- rescale cacc: alpha per q-row qd*4+r, broadcast from lane qd*4+r ----
    const float a0 = __shfl(al, qd * 4 + 0, 64);
    const float a1 = __shfl(al, qd * 4 + 1, 64);
    const float a2 = __shfl(al, qd * 4 + 2, 64);
    const float a3 = __shfl(al, qd * 4 + 3, 64);
#pragma unroll
    for (int t = 0; t < 4; t++) {
      cacc[t][0] *= a0; cacc[t][1] *= a1;
      cacc[t][2] *= a2; cacc[t][3] *= a3;
    }

    // ---- PV (8 MFMA): P from wave-private Ps, V from LDS tile ----
    bfrag pa[2];
#pragma unroll
    for (int s = 0; s < 2; s++)
      pa[s] = *(bfrag*)&Ps[(wv * 16 + ln) * PSTR + s * 32 + qd * 8];
#pragma unroll
    for (int t = 0; t < 4; t++)
#pragma unroll
      for (int s = 0; s < 2; s++) {
        bfrag vbf = *(bfrag*)&Vs[(t * 16 + ln) * KSTR + s * 32 + qd * 8];
        cacc[t] = MFMA16(pa[s], vbf, cacc[t]);
      }

    // ---- E copy: wave-private Ps rows -> global (nontemporal, vectorized) ----
#pragma unroll
    for (int c = 0; c < 2; c++) {
      const int row = wv * 16 + (lane >> 3) + c * 8;
      const int ch = lane & 7;
      f4 ev = *(f4*)&Ps[row * PSTR + ch * 8];
      __builtin_nontemporal_store(
          ev, (f4*)&E[((size_t)bh * S_ + q0b + row) * S_ + kt + ch * 8]);
    }
  }

  // ---- epilogue ----
  l += __shfl_xor(l, 16, 64);
  l += __shfl_xor(l, 32, 64);
  const float inv = 1.0f / l;
  const float i0 = __shfl(inv, qd * 4 + 0, 64);
  const float i1 = __shfl(inv, qd * 4 + 1, 64);
  const float i2 = __shfl(inv, qd * 4 + 2, 64);
  const float i3 = __shfl(inv, qd * 4 + 3, 64);
  const int b = bh >> 3, h = bh & 7;
#pragma unroll
  for (int t = 0; t < 4; t++) {
    CTXb[((size_t)b * S_ + q0w + qd * 4 + 0) * D_ + h * DK_ + t * 16 + ln] = (__bf16)(cacc[t][0] * i0);
    CTXb[((size_t)b * S_ + q0w + qd * 4 + 1) * D_ + h * DK_ + t * 16 + ln] = (__bf16)(cacc[t][1] * i1);
    CTXb[((size_t)b * S_ + q0w + qd * 4 + 2) * D_ + h * DK_ + t * 16 + ln] = (__bf16)(cacc[t][2] * i2);
    CTXb[((size_t)b * S_ + q0w + qd * 4 + 3) * D_ + h * DK_ + t * 16 + ln] = (__bf16)(cacc[t][3] * i3);
  }
  if (qd == 0) {
    MR[(size_t)bh * S_ + q0w + ln] = m;
    LR[(size_t)bh * S_ + q0w + ln] = l;
  }
}

// ---------------------------------------------------------------------------
// mean = (1/8) sum_h E * exp(MT - m_fin) / l_fin  — bandwidth kernel.
// mf/il hoisted out of the kc loop. Grid (S/32, B, 4 kv-slices).
// ---------------------------------------------------------------------------
__global__ __launch_bounds__(256) void mean_rescale(
    const __bf16* __restrict__ E, const float* __restrict__ MT,
    const float* __restrict__ MR, const float* __restrict__ LR,
    float* __restrict__ meanout) {
  const int t = threadIdx.x;
  const int qr = t >> 3, seg = t & 7;
  const int b = blockIdx.y, ks = blockIdx.z;
  const int qg = blockIdx.x * 32 + qr;

  float mf[H_], il[H_];
#pragma unroll
  for (int h = 0; h < H_; h++) {
    const int bh = b * H_ + h;
    mf[h] = MR[(size_t)bh * S_ + qg];
    il[h] = 1.0f / LR[(size_t)bh * S_ + qg];
  }

  for (int kc = 0; kc < 8; kc++) {
    const int k0 = ks * 512 + kc * 64;
    const int tk = k0 >> 6;
    float acc[8];
#pragma unroll
    for (int j = 0; j < 8; j++) acc[j] = 0.f;
#pragma unroll
    for (int h = 0; h < H_; h++) {
      const int bh = b * H_ + h;
      const float mt = MT[((size_t)bh * 32 + tk) * S_ + qg];
      const float sc = __expf(mt - mf[h]) * il[h];
      bfrag e = __builtin_nontemporal_load(
          (const bfrag*)&E[((size_t)bh * S_ + qg) * S_ + k0 + seg * 8]);
#pragma unroll
      for (int j = 0; j < 8; j++) acc[j] += (float)e[j] * sc;
    }
    f4 o0, o1;
    o0[0] = acc[0] * 0.125f; o0[1] = acc[1] * 0.125f;
    o0[2] = acc[2] * 0.125f; o0[3] = acc[3] * 0.125f;
    o1[0] = acc[4] * 0.125f; o1[1] = acc[5] * 0.125f;
    o1[2] = acc[6] * 0.125f; o1[3] = acc[7] * 0.125f;
    float* mp = &meanout[((size_t)b * S_ + qg) * S_ + k0 + seg * 8];
    *(f4*)&mp[0] = o0;
    *(f4*)&mp[4] = o1;
  }
}

// ---------------------------------------------------------------------------
extern "C" void kernel_launch(void* const* d_in, const int* in_sizes, int n_in,
                              void* d_out, int out_size, void* d_ws, size_t ws_size,
                              hipStream_t stream) {
  (void)in_sizes; (void)n_in; (void)out_size; (void)ws_size;
  const float* Zq = (const float*)d_in[0];
  const float* Zkv = (const float*)d_in[1];
  const float* mask = (const float*)d_in[2];
  const float* Wqkv = (const float*)d_in[3];
  const float* Wout = (const float*)d_in[4];

  float* out = (float*)d_out;                // [B,S,D]
  float* mean = out + (size_t)B_ * S_ * D_;  // [B,S,S]

  char* w = (char*)d_ws;
  const size_t WSZ = 512 * 512 * sizeof(__bf16);
  const size_t QSZ = (size_t)B_ * H_ * S_ * DK_ * sizeof(__bf16);
  __bf16* WqTh = (__bf16*)w; w += WSZ;
  __bf16* WqTl = (__bf16*)w; w += WSZ;
  __bf16* WkTh = (__bf16*)w; w += WSZ;
  __bf16* WkTl = (__bf16*)w; w += WSZ;
  __bf16* WvTh = (__bf16*)w; w += WSZ;
  __bf16* WoTh = (__bf16*)w; w += WSZ;
  __bf16* Qh = (__bf16*)w; w += QSZ;
  __bf16* Ql = (__bf16*)w; w += QSZ;
  __bf16* Kh = (__bf16*)w; w += QSZ;
  __bf16* Kl = (__bf16*)w; w += QSZ;
  __bf16* VTh = (__bf16*)w; w += QSZ;
  __bf16* CTXb = (__bf16*)w; w += QSZ;
  float* MR = (float*)w; w += (size_t)B_ * H_ * S_ * sizeof(float);
  float* LR = (float*)w; w += (size_t)B_ * H_ * S_ * sizeof(float);
  float* MT = (float*)w; w += (size_t)B_ * H_ * 32 * S_ * sizeof(float);   // 8.4 MB
  __bf16* E = (__bf16*)w; w += (size_t)B_ * H_ * S_ * S_ * sizeof(__bf16); // 268 MB

  wtr<<<1024, 256, 0, stream>>>(Wqkv, 1536, 0, WqTh, WqTl, 1);
  wtr<<<1024, 256, 0, stream>>>(Wqkv, 1536, 512, WkTh, WkTl, 1);
  wtr<<<1024, 256, 0, stream>>>(Wqkv, 1536, 1024, WvTh, nullptr, 0);
  wtr<<<1024, 256, 0, stream>>>(Wout, 512, 0, WoTh, nullptr, 0);

  gemm_mfma<true, false, true, 1><<<dim3(8, 128), 256, 0, stream>>>(
      Zq, WqTh, WqTl, nullptr, Qh, Ql);
  gemm_mfma<true, false, true, 1><<<dim3(8, 128), 256, 0, stream>>>(
      Zkv, WkTh, WkTl, nullptr, Kh, Kl);
  gemm_mfma<false, true, false, 2><<<dim3(128, 8), 256, 0, stream>>>(
      WvTh, Zkv, nullptr, nullptr, VTh, nullptr);

  attn_fctx<<<dim3(32, 32), 256, 0, stream>>>(Qh, Ql, Kh, Kl, VTh, mask, CTXb, MR, LR, E, MT);
  mean_rescale<<<dim3(64, 4, 4), 256, 0, stream>>>(E, MT, MR, LR, mean);

  gemm_mfma<false, false, false, 0><<<dim3(8, 128), 256, 0, stream>>>(
      CTXb, WoTh, nullptr, out, nullptr, nullptr);
}

// Round 9
// 390.230 us; speedup vs baseline: 1.9623x; 1.0604x over previous
//
#include <hip/hip_runtime.h>
#include <cstdint>

#define B_ 4
#define S_ 2048
#define D_ 512
#define H_ 8
#define DK_ 64
#define SCALE 0.125f
#define KSTR 84   // K/V LDS row stride in bf16 (measured conflict-free)
#define PSTR 68   // Ps LDS row stride in bf16 (measured conflict-free)

using bfrag = __attribute__((ext_vector_type(8))) __bf16;
using b4    = __attribute__((ext_vector_type(4))) __bf16;
using f4    = __attribute__((ext_vector_type(4))) float;
using f16v  = __attribute__((ext_vector_type(16))) float;

#define MFMA16(a, b, c) __builtin_amdgcn_mfma_f32_16x16x32_bf16(a, b, c, 0, 0, 0)
#define MFMA32(a, b, c) __builtin_amdgcn_mfma_f32_32x32x16_bf16(a, b, c, 0, 0, 0)

// ---------------------------------------------------------------------------
// All 4 weight transposes in one launch: grid (1024, 4).
// by 0..2: Wqkv col-block by (hi+lo for 0,1; hi only for 2). by 3: Wout hi.
// ---------------------------------------------------------------------------
__global__ __launch_bounds__(256) void wtr_all(
    const float* __restrict__ Wqkv, const float* __restrict__ Wout,
    __bf16* __restrict__ WqTh, __bf16* __restrict__ WqTl,
    __bf16* __restrict__ WkTh, __bf16* __restrict__ WkTl,
    __bf16* __restrict__ WvTh, __bf16* __restrict__ WoTh) {
  const int by = blockIdx.y;
  const int idx = blockIdx.x * 256 + threadIdx.x;  // 512*512
  const int k = idx & 511, n = idx >> 9;
  const float* W = (by == 3) ? Wout : Wqkv;
  const int ldw = (by == 3) ? 512 : 1536;
  const int c0 = (by == 3) ? 0 : by * 512;
  const float x = W[(size_t)k * ldw + c0 + n];
  const __bf16 h = (__bf16)x;
  __bf16* th = (by == 0) ? WqTh : (by == 1) ? WkTh : (by == 2) ? WvTh : WoTh;
  th[(size_t)n * 512 + k] = h;
  if (by < 2) {
    __bf16* tl = (by == 0) ? WqTl : WkTl;
    tl[(size_t)n * 512 + k] = (__bf16)(x - (float)h);
  }
}

// ---------------------------------------------------------------------------
// Split-bf16 MFMA GEMM (unchanged — passed rounds 2-8).
// ---------------------------------------------------------------------------
template <bool AF32, bool BF32, bool LO, int MODE>
__global__ __launch_bounds__(256) void gemm_mfma(
    const void* __restrict__ Ap, const void* __restrict__ Bp, const void* __restrict__ Blop,
    float* __restrict__ Cf, __bf16* __restrict__ Oh, __bf16* __restrict__ Ol) {
  __shared__ __bf16 Ash[64 * 40];
  __shared__ __bf16 Asl[64 * 40];
  __shared__ __bf16 Bsh[64 * 40];
  __shared__ __bf16 Bsl[64 * 40];

  const int tid = threadIdx.x;
  const int m0 = blockIdx.y * 64, n0 = blockIdx.x * 64;
  const int row = tid >> 2, seg = tid & 3;
  const int lane = tid & 63, wv = tid >> 6;
  const int wm = (wv & 1) * 32, wn = (wv >> 1) * 32;
  const int qd = lane >> 4, ln = lane & 15;

  f4 acc[2][2];
#pragma unroll
  for (int i = 0; i < 2; i++)
#pragma unroll
    for (int j = 0; j < 2; j++)
#pragma unroll
      for (int r = 0; r < 4; r++) acc[i][j][r] = 0.f;

  for (int kt = 0; kt < 512; kt += 32) {
    const size_t abase = (size_t)(m0 + row) * 512 + kt + seg * 8;
    const size_t bbase = (size_t)(n0 + row) * 512 + kt + seg * 8;
    float4 a0, a1, b0, b1, bl0;
    if constexpr (AF32) {
      const float* A = (const float*)Ap;
      a0 = *(const float4*)&A[abase];
      a1 = *(const float4*)&A[abase + 4];
    } else {
      const __bf16* A = (const __bf16*)Ap;
      a0 = *(const float4*)&A[abase];
    }
    if constexpr (BF32) {
      const float* Bm = (const float*)Bp;
      b0 = *(const float4*)&Bm[bbase];
      b1 = *(const float4*)&Bm[bbase + 4];
    } else {
      const __bf16* Bm = (const __bf16*)Bp;
      b0 = *(const float4*)&Bm[bbase];
      if constexpr (LO) {
        const __bf16* Bl = (const __bf16*)Blop;
        bl0 = *(const float4*)&Bl[bbase];
      }
    }
    __syncthreads();
    if constexpr (AF32) {
      float x[8] = {a0.x, a0.y, a0.z, a0.w, a1.x, a1.y, a1.z, a1.w};
      bfrag h, l;
#pragma unroll
      for (int j = 0; j < 8; j++) {
        h[j] = (__bf16)x[j];
        l[j] = (__bf16)(x[j] - (float)h[j]);
      }
      *(bfrag*)&Ash[row * 40 + seg * 8] = h;
      if constexpr (LO) *(bfrag*)&Asl[row * 40 + seg * 8] = l;
    } else {
      *(float4*)&Ash[row * 40 + seg * 8] = a0;
    }
    if constexpr (BF32) {
      float x[8] = {b0.x, b0.y, b0.z, b0.w, b1.x, b1.y, b1.z, b1.w};
      bfrag h;
#pragma unroll
      for (int j = 0; j < 8; j++) h[j] = (__bf16)x[j];
      *(bfrag*)&Bsh[row * 40 + seg * 8] = h;
    } else {
      *(float4*)&Bsh[row * 40 + seg * 8] = b0;
      if constexpr (LO) *(float4*)&Bsl[row * 40 + seg * 8] = bl0;
    }
    __syncthreads();

    bfrag ah[2], al[2], bh[2], bl[2];
#pragma unroll
    for (int mi = 0; mi < 2; mi++) {
      ah[mi] = *(bfrag*)&Ash[(wm + mi * 16 + ln) * 40 + qd * 8];
      if constexpr (LO) al[mi] = *(bfrag*)&Asl[(wm + mi * 16 + ln) * 40 + qd * 8];
    }
#pragma unroll
    for (int ni = 0; ni < 2; ni++) {
      bh[ni] = *(bfrag*)&Bsh[(wn + ni * 16 + ln) * 40 + qd * 8];
      if constexpr (LO) bl[ni] = *(bfrag*)&Bsl[(wn + ni * 16 + ln) * 40 + qd * 8];
    }
#pragma unroll
    for (int mi = 0; mi < 2; mi++)
#pragma unroll
      for (int ni = 0; ni < 2; ni++) {
        acc[mi][ni] = MFMA16(ah[mi], bh[ni], acc[mi][ni]);
        if constexpr (LO) {
          acc[mi][ni] = MFMA16(ah[mi], bl[ni], acc[mi][ni]);
          acc[mi][ni] = MFMA16(al[mi], bh[ni], acc[mi][ni]);
        }
      }
  }

#pragma unroll
  for (int mi = 0; mi < 2; mi++)
#pragma unroll
    for (int ni = 0; ni < 2; ni++)
#pragma unroll
      for (int r = 0; r < 4; r++) {
        const int mrow = m0 + wm + mi * 16 + qd * 4 + r;
        const int ncol = n0 + wn + ni * 16 + ln;
        const float c = acc[mi][ni][r];
        if constexpr (MODE == 0) {
          Cf[(size_t)mrow * 512 + ncol] = c;
        } else if constexpr (MODE == 1) {
          const int b = mrow >> 11, s = mrow & (S_ - 1);
          const int h = ncol >> 6, dk = ncol & 63;
          const size_t o = (((size_t)b * H_ + h) * S_ + s) * DK_ + dk;
          __bf16 hh = (__bf16)c;
          Oh[o] = hh;
          Ol[o] = (__bf16)(c - (float)hh);
        } else {  // MODE 2: V^T
          const int h = mrow >> 6, dk = mrow & 63;
          const int b = ncol >> 11, s = ncol & (S_ - 1);
          Oh[(((size_t)b * H_ + h) * DK_ + dk) * S_ + s] = (__bf16)c;
        }
      }
}

// ---------------------------------------------------------------------------
// Fused flash attention, 32 q/wave via 32x32x16 QK (transposed scores):
// z^T = K·Q^T: A=K (m=kv), B=Q (n=q); D: col=lane&31 (=q),
// row=(reg&3)+8*(reg>>2)+4*(lane>>5) (=kv). Same 16 K-frag b128 reads and
// 24 MFMAs per tile as R8 but for 2x the q — per-q QK LDS halved.
// Softmax scalar/lane; tile reduce = 1 shfl_xor(32). alpha/inv via per-wave
// LDS f32 array (b128 reads). PV stays 16-shape (2 m-tiles). E/MT unchanged.
// Block 256 = 4 waves x 32 q = 128 q; grid (S/128, B*H) = 512.
// ---------------------------------------------------------------------------
__global__ __launch_bounds__(256) void attn_fctx(
    const __bf16* __restrict__ Qh_, const __bf16* __restrict__ Ql_,
    const __bf16* __restrict__ Kh_, const __bf16* __restrict__ Kl_,
    const __bf16* __restrict__ VT, const float* __restrict__ mask,
    __bf16* __restrict__ CTXb, float* __restrict__ MR, float* __restrict__ LR,
    __bf16* __restrict__ E, float* __restrict__ MT) {
  __shared__ __bf16 Ksh[64 * KSTR];
  __shared__ __bf16 Ksl[64 * KSTR];
  __shared__ __bf16 Vs[64 * KSTR];
  __shared__ __bf16 Ps[128 * PSTR];
  __shared__ float als[128];
  const int tid = threadIdx.x, lane = tid & 63, wv = tid >> 6;
  const int l31 = lane & 31, kh = lane >> 5;
  const int qd = lane >> 4, ln = lane & 15;
  const int bh = blockIdx.y;
  const int q0b = blockIdx.x * 128;
  const int q0w = q0b + wv * 32;
  const int srow = tid >> 2, sseg = tid & 3;

  // Q fragments (B-operand, 32x32x16): n = q = l31, k = ks*16 + kh*8 + j
  bfrag qhf[4], qlf[4];
#pragma unroll
  for (int ks = 0; ks < 4; ks++) {
    const size_t qb = ((size_t)bh * S_ + q0w + l31) * DK_ + ks * 16 + kh * 8;
    qhf[ks] = *(const bfrag*)&Qh_[qb];
    qlf[ks] = *(const bfrag*)&Ql_[qb];
  }

  float m = -3.0e38f, l = 0.f;   // per lane: q = q0w + l31 (dup across halves)
  f4 cacc[2][4];                  // [mt][nt] — PV 16-shape accumulators
#pragma unroll
  for (int mt = 0; mt < 2; mt++)
#pragma unroll
    for (int nt = 0; nt < 4; nt++)
#pragma unroll
      for (int r = 0; r < 4; r++) cacc[mt][nt][r] = 0.f;

  // prefetch tile 0
  float4 h0, h1, l0, l1, v0, v1;
  {
    const size_t kb = ((size_t)bh * S_ + srow) * DK_ + sseg * 16;
    const size_t vb = ((size_t)bh * DK_ + srow) * S_ + sseg * 16;
    h0 = *(const float4*)&Kh_[kb]; h1 = *(const float4*)&Kh_[kb + 8];
    l0 = *(const float4*)&Kl_[kb]; l1 = *(const float4*)&Kl_[kb + 8];
    v0 = *(const float4*)&VT[vb];  v1 = *(const float4*)&VT[vb + 8];
  }

  for (int kt = 0; kt < S_; kt += 64) {
    __syncthreads();
    *(float4*)&Ksh[srow * KSTR + sseg * 16] = h0;
    *(float4*)&Ksh[srow * KSTR + sseg * 16 + 8] = h1;
    *(float4*)&Ksl[srow * KSTR + sseg * 16] = l0;
    *(float4*)&Ksl[srow * KSTR + sseg * 16 + 8] = l1;
    *(float4*)&Vs[srow * KSTR + sseg * 16] = v0;
    *(float4*)&Vs[srow * KSTR + sseg * 16 + 8] = v1;
    __syncthreads();

    // mask, transposed order: entry (q = q0w+l31, kv = kt + t*32 + g*8 + 4*kh + i)
    f4 mk[2][4];
#pragma unroll
    for (int t = 0; t < 2; t++)
#pragma unroll
      for (int g = 0; g < 4; g++)
        mk[t][g] = *(const f4*)&mask[(size_t)(q0w + l31) * S_ + kt + t * 32 + g * 8 + 4 * kh];

    // prefetch next tile
    if (kt + 64 < S_) {
      const size_t kb = ((size_t)bh * S_ + kt + 64 + srow) * DK_ + sseg * 16;
      const size_t vb = ((size_t)bh * DK_ + srow) * S_ + kt + 64 + sseg * 16;
      h0 = *(const float4*)&Kh_[kb]; h1 = *(const float4*)&Kh_[kb + 8];
      l0 = *(const float4*)&Kl_[kb]; l1 = *(const float4*)&Kl_[kb + 8];
      v0 = *(const float4*)&VT[vb];  v1 = *(const float4*)&VT[vb + 8];
    }

    // ---- z^T = K·Q^T, 32x32x16 split-3: 16 b128 reads, 24 MFMAs, 32 q ----
    f16v z[2];
#pragma unroll
    for (int t = 0; t < 2; t++)
#pragma unroll
      for (int r = 0; r < 16; r++) z[t][r] = 0.f;
#pragma unroll
    for (int t = 0; t < 2; t++)
#pragma unroll
      for (int ks = 0; ks < 4; ks++) {
        bfrag kbh = *(bfrag*)&Ksh[(t * 32 + l31) * KSTR + ks * 16 + kh * 8];
        bfrag kbl = *(bfrag*)&Ksl[(t * 32 + l31) * KSTR + ks * 16 + kh * 8];
        z[t] = MFMA32(kbh, qhf[ks], z[t]);
        z[t] = MFMA32(kbl, qhf[ks], z[t]);
        z[t] = MFMA32(kbh, qlf[ks], z[t]);
      }

    // ---- scale + mask in place ----
#pragma unroll
    for (int t = 0; t < 2; t++)
#pragma unroll
      for (int r = 0; r < 16; r++)
        z[t][r] = fmaf(z[t][r], SCALE, mk[t][r >> 2][r & 3]);

    // ---- online softmax: per-lane q column, 1 cross-lane reduce ----
    float tm = z[0][0];
#pragma unroll
    for (int t = 0; t < 2; t++)
#pragma unroll
      for (int r = 0; r < 16; r++) tm = fmaxf(tm, z[t][r]);
    tm = fmaxf(tm, __shfl_xor(tm, 32, 64));
    const float nm = fmaxf(m, tm);
    const float al = __expf(m - nm);
    m = nm;
    if (lane < 32) als[wv * 32 + lane] = al;

    float ls = 0.f;
#pragma unroll
    for (int t = 0; t < 2; t++)
#pragma unroll
      for (int g = 0; g < 4; g++) {
        const float e0 = __expf(z[t][g * 4 + 0] - nm);
        const float e1 = __expf(z[t][g * 4 + 1] - nm);
        const float e2 = __expf(z[t][g * 4 + 2] - nm);
        const float e3 = __expf(z[t][g * 4 + 3] - nm);
        ls += (e0 + e1) + (e2 + e3);
        b4 pk;
        pk[0] = (__bf16)e0; pk[1] = (__bf16)e1;
        pk[2] = (__bf16)e2; pk[3] = (__bf16)e3;
        *(b4*)&Ps[(wv * 32 + l31) * PSTR + t * 32 + g * 8 + 4 * kh] = pk;
      }
    l = l * al + ls;

    if (lane < 32)
      MT[((size_t)bh * 32 + (kt >> 6)) * S_ + q0w + lane] = m;

    // ---- rescale cacc with alpha from LDS (row q = mt*16 + qd*4 + r) ----
#pragma unroll
    for (int mt = 0; mt < 2; mt++) {
      f4 av = *(f4*)&als[wv * 32 + mt * 16 + qd * 4];
#pragma unroll
      for (int nt = 0; nt < 4; nt++)
#pragma unroll
        for (int r = 0; r < 4; r++) cacc[mt][nt][r] *= av[r];
    }

    // ---- PV (16 MFMA, 16-shape): P m=q (2 tiles), V n=d (4 tiles), k=kv ----
    bfrag pa[2][2];
#pragma unroll
    for (int mt = 0; mt < 2; mt++)
#pragma unroll
      for (int ks = 0; ks < 2; ks++)
        pa[mt][ks] = *(bfrag*)&Ps[(wv * 32 + mt * 16 + ln) * PSTR + ks * 32 + qd * 8];
#pragma unroll
    for (int nt = 0; nt < 4; nt++)
#pragma unroll
      for (int ks = 0; ks < 2; ks++) {
        bfrag vbf = *(bfrag*)&Vs[(nt * 16 + ln) * KSTR + ks * 32 + qd * 8];
#pragma unroll
        for (int mt = 0; mt < 2; mt++)
          cacc[mt][nt] = MFMA16(pa[mt][ks], vbf, cacc[mt][nt]);
      }

    // ---- E copy: wave-private Ps rows -> global (vectorized, coalesced) ----
#pragma unroll
    for (int c = 0; c < 4; c++) {
      const int row = wv * 32 + (lane >> 3) + c * 8;
      const int ch = lane & 7;
      f4 ev = *(f4*)&Ps[row * PSTR + ch * 8];
      __builtin_nontemporal_store(
          ev, (f4*)&E[((size_t)bh * S_ + q0b + row) * S_ + kt + ch * 8]);
    }
  }

  // ---- epilogue ----
  l += __shfl_xor(l, 32, 64);
  if (lane < 32) {
    MR[(size_t)bh * S_ + q0w + lane] = m;
    LR[(size_t)bh * S_ + q0w + lane] = l;
    als[wv * 32 + lane] = 1.0f / l;
  }
  const int b = bh >> 3, h = bh & 7;
#pragma unroll
  for (int mt = 0; mt < 2; mt++) {
    f4 iv = *(f4*)&als[wv * 32 + mt * 16 + qd * 4];
#pragma unroll
    for (int nt = 0; nt < 4; nt++)
#pragma unroll
      for (int r = 0; r < 4; r++)
        CTXb[((size_t)b * S_ + q0w + mt * 16 + qd * 4 + r) * D_ + h * DK_ + nt * 16 + ln] =
            (__bf16)(cacc[mt][nt][r] * iv[r]);
  }
}

// ---------------------------------------------------------------------------
// mean = (1/8) sum_h E * exp(MT - m_fin) / l_fin  — bandwidth kernel.
// (unchanged from R8 — verified)
// ---------------------------------------------------------------------------
__global__ __launch_bounds__(256) void mean_rescale(
    const __bf16* __restrict__ E, const float* __restrict__ MT,
    const float* __restrict__ MR, const float* __restrict__ LR,
    float* __restrict__ meanout) {
  const int t = threadIdx.x;
  const int qr = t >> 3, seg = t & 7;
  const int b = blockIdx.y, ks = blockIdx.z;
  const int qg = blockIdx.x * 32 + qr;

  float mf[H_], il[H_];
#pragma unroll
  for (int h = 0; h < H_; h++) {
    const int bh = b * H_ + h;
    mf[h] = MR[(size_t)bh * S_ + qg];
    il[h] = 1.0f / LR[(size_t)bh * S_ + qg];
  }

  for (int kc = 0; kc < 8; kc++) {
    const int k0 = ks * 512 + kc * 64;
    const int tk = k0 >> 6;
    float acc[8];
#pragma unroll
    for (int j = 0; j < 8; j++) acc[j] = 0.f;
#pragma unroll
    for (int h = 0; h < H_; h++) {
      const int bh = b * H_ + h;
      const float mt = MT[((size_t)bh * 32 + tk) * S_ + qg];
      const float sc = __expf(mt - mf[h]) * il[h];
      bfrag e = __builtin_nontemporal_load(
          (const bfrag*)&E[((size_t)bh * S_ + qg) * S_ + k0 + seg * 8]);
#pragma unroll
      for (int j = 0; j < 8; j++) acc[j] += (float)e[j] * sc;
    }
    f4 o0, o1;
    o0[0] = acc[0] * 0.125f; o0[1] = acc[1] * 0.125f;
    o0[2] = acc[2] * 0.125f; o0[3] = acc[3] * 0.125f;
    o1[0] = acc[4] * 0.125f; o1[1] = acc[5] * 0.125f;
    o1[2] = acc[6] * 0.125f; o1[3] = acc[7] * 0.125f;
    float* mp = &meanout[((size_t)b * S_ + qg) * S_ + k0 + seg * 8];
    *(f4*)&mp[0] = o0;
    *(f4*)&mp[4] = o1;
  }
}

// ---------------------------------------------------------------------------
extern "C" void kernel_launch(void* const* d_in, const int* in_sizes, int n_in,
                              void* d_out, int out_size, void* d_ws, size_t ws_size,
                              hipStream_t stream) {
  (void)in_sizes; (void)n_in; (void)out_size; (void)ws_size;
  const float* Zq = (const float*)d_in[0];
  const float* Zkv = (const float*)d_in[1];
  const float* mask = (const float*)d_in[2];
  const float* Wqkv = (const float*)d_in[3];
  const float* Wout = (const float*)d_in[4];

  float* out = (float*)d_out;                // [B,S,D]
  float* mean = out + (size_t)B_ * S_ * D_;  // [B,S,S]

  char* w = (char*)d_ws;
  const size_t WSZ = 512 * 512 * sizeof(__bf16);
  const size_t QSZ = (size_t)B_ * H_ * S_ * DK_ * sizeof(__bf16);
  __bf16* WqTh = (__bf16*)w; w += WSZ;
  __bf16* WqTl = (__bf16*)w; w += WSZ;
  __bf16* WkTh = (__bf16*)w; w += WSZ;
  __bf16* WkTl = (__bf16*)w; w += WSZ;
  __bf16* WvTh = (__bf16*)w; w += WSZ;
  __bf16* WoTh = (__bf16*)w; w += WSZ;
  __bf16* Qh = (__bf16*)w; w += QSZ;
  __bf16* Ql = (__bf16*)w; w += QSZ;
  __bf16* Kh = (__bf16*)w; w += QSZ;
  __bf16* Kl = (__bf16*)w; w += QSZ;
  __bf16* VTh = (__bf16*)w; w += QSZ;
  __bf16* CTXb = (__bf16*)w; w += QSZ;
  float* MR = (float*)w; w += (size_t)B_ * H_ * S_ * sizeof(float);
  float* LR = (float*)w; w += (size_t)B_ * H_ * S_ * sizeof(float);
  float* MT = (float*)w; w += (size_t)B_ * H_ * 32 * S_ * sizeof(float);   // 8.4 MB
  __bf16* E = (__bf16*)w; w += (size_t)B_ * H_ * S_ * S_ * sizeof(__bf16); // 268 MB

  wtr_all<<<dim3(1024, 4), 256, 0, stream>>>(Wqkv, Wout, WqTh, WqTl, WkTh, WkTl, WvTh, WoTh);

  gemm_mfma<true, false, true, 1><<<dim3(8, 128), 256, 0, stream>>>(
      Zq, WqTh, WqTl, nullptr, Qh, Ql);
  gemm_mfma<true, false, true, 1><<<dim3(8, 128), 256, 0, stream>>>(
      Zkv, WkTh, WkTl, nullptr, Kh, Kl);
  gemm_mfma<false, true, false, 2><<<dim3(128, 8), 256, 0, stream>>>(
      WvTh, Zkv, nullptr, nullptr, VTh, nullptr);

  attn_fctx<<<dim3(16, 32), 256, 0, stream>>>(Qh, Ql, Kh, Kl, VTh, mask, CTXb, MR, LR, E, MT);
  mean_rescale<<<dim3(64, 4, 4), 256, 0, stream>>>(E, MT, MR, LR, mean);

  gemm_mfma<false, false, false, 0><<<dim3(8, 128), 256, 0, stream>>>(
      CTXb, WoTh, nullptr, out, nullptr, nullptr);
}